// Round 1
// baseline (475.068 us; speedup 1.0000x reference)
//
#include <hip/hip_runtime.h>

// LocalAffinity, restructured: one block = one (k, tap) x one z-slice.
// out[k,t,z,y,x] = x[k,z,y,x] - x[k, clamp(z+di*d), clamp(y+dj*d), clamp(x+dk*d)]
// 26 taps (raster (i,j,k) skipping center) at d=1 then d=2.
// B=1, K=2, D=64, H=128, W=128. Output 436 MB -> write-BW-bound.
// Each wave emits ONE contiguous store stream (vs 52 scattered 4MB-strided
// streams before); 6656 blocks give ~26 generations/CU of pipelining.

constexpr int Dz   = 64;
constexpr int Hy   = 128;
constexpr int Wx   = 128;
constexpr int HW   = Hy * Wx;        // 16384
constexpr int DHW  = Dz * HW;        // 1048576
constexpr int TAPS = 52;

typedef float floatx4   __attribute__((ext_vector_type(4)));
typedef float floatx4_u __attribute__((ext_vector_type(4), aligned(4)));

__device__ __forceinline__ int iclamp(int v, int lo, int hi) {
    return v < lo ? lo : (v > hi ? hi : v);
}

__global__ __launch_bounds__(256)
void LocalAffinity_kernel(const float* __restrict__ in, float* __restrict__ out) {
    // Grid: 2(k) * 52(t) * 64(z) = 6656 blocks.
    // bid % 8 = XCD (round-robin dispatch); k = bid & 1 pins each k's 4 MB
    // input plane to a fixed set of XCD L2s. Blocks resident together on one
    // XCD step t by 4 at fixed z -> same input rows re-read while L2-hot.
    const int bid  = blockIdx.x;
    const int k    = bid & 1;
    const int rest = bid >> 1;           // 0..3327 = z*52 + t
    const int t    = rest % TAPS;
    const int z    = rest / TAPS;

    // Decode tap t -> (d, di, dj, dk). All block-uniform (scalar).
    const int d   = (t < 26) ? 1 : 2;
    const int t26 = (t < 26) ? t : t - 26;
    const int ras = (t26 < 13) ? t26 : t26 + 1;   // re-insert skipped center
    const int di  = ras / 9 - 1;
    const int dj  = (ras % 9) / 3 - 1;
    const int dk  = (ras % 3) - 1;
    const int dkd = dk * d;
    const int dy  = dj * d;
    const int zc  = iclamp(z + di * d, 0, Dz - 1);

    const float* __restrict__ ctr = in + k * DHW + z  * HW;  // center z-plane
    const float* __restrict__ src = in + k * DHW + zc * HW;  // clamped z-plane
    float* __restrict__ o = out + (size_t)(k * TAPS + t) * (size_t)DHW
                                + (size_t)z * HW;

    const int tid = threadIdx.x;

    #pragma unroll
    for (int i = 0; i < 16; ++i) {
        const int pos = (i << 8) | tid;   // float4 slot in z-slice, [0,4096)
        const int y   = pos >> 5;
        const int x4  = pos & 31;
        const int x0  = x4 << 2;

        const floatx4 c = *(const floatx4*)(ctr + y * Wx + x0);

        const int yc = iclamp(y + dy, 0, Hy - 1);
        const float* row = src + yc * Wx;

        floatx4 s;
        if (dkd == 0) {
            s = *(const floatx4*)(row + x0);
        } else {
            // Unaligned (dword-aligned) vector load at the shifted position,
            // start clamped into the row; repair the 1-2 clamped lanes.
            const int xs  = x0 + dkd;
            const int xsa = iclamp(xs, 0, Wx - 4);
            const floatx4 v = *(const floatx4_u*)(row + xsa);
            s = v;
            if (dkd < 0) {                 // block-uniform branch
                const bool e = (x4 == 0);  // per-lane predication only here
                if (dkd == -1) {
                    if (e) { s.x = v.x; s.y = v.x; s.z = v.y; s.w = v.z; }
                } else {                   // dkd == -2
                    if (e) { s.x = v.x; s.y = v.x; s.z = v.x; s.w = v.y; }
                }
            } else {
                const bool e = (x4 == 31);
                if (dkd == 1) {
                    if (e) { s.x = v.y; s.y = v.z; s.z = v.w; s.w = v.w; }
                } else {                   // dkd == 2
                    if (e) { s.x = v.z; s.y = v.w; s.z = v.w; s.w = v.w; }
                }
            }
        }

        floatx4 r;
        r.x = c.x - s.x; r.y = c.y - s.y; r.z = c.z - s.z; r.w = c.w - s.w;
        __builtin_nontemporal_store(r, (floatx4*)(o + (size_t)pos * 4));
    }
}

extern "C" void kernel_launch(void* const* d_in, const int* in_sizes, int n_in,
                              void* d_out, int out_size, void* d_ws, size_t ws_size,
                              hipStream_t stream) {
    const float* x = (const float*)d_in[0];
    float* out = (float*)d_out;
    LocalAffinity_kernel<<<2 * TAPS * Dz, 256, 0, stream>>>(x, out);
}

// Round 2
// 471.990 us; speedup vs baseline: 1.0065x; 1.0065x over previous
//
#include <hip/hip_runtime.h>

// LocalAffinity: one block = one (k, tap) x one z-slice.
// out[k,t,z,y,x] = x[k,z,y,x] - x[k, clamp(z+di*d), clamp(y+dj*d), clamp(x+dk*d)]
// 26 taps (raster (i,j,k) skipping center) at d=1 then d=2.
// B=1, K=2, D=64, H=128, W=128. Output 436 MB -> write-BW-bound.
// R2 change: PLAIN stores instead of nontemporal. The harness's own
// fillBuffer sustains 6.4 TB/s with cached stores; both prior kernels
// (~1-2.2 TB/s) used nt stores -> testing nt as the common cap.

constexpr int Dz   = 64;
constexpr int Hy   = 128;
constexpr int Wx   = 128;
constexpr int HW   = Hy * Wx;        // 16384
constexpr int DHW  = Dz * HW;        // 1048576
constexpr int TAPS = 52;

typedef float floatx4   __attribute__((ext_vector_type(4)));
typedef float floatx4_u __attribute__((ext_vector_type(4), aligned(4)));

__device__ __forceinline__ int iclamp(int v, int lo, int hi) {
    return v < lo ? lo : (v > hi ? hi : v);
}

__global__ __launch_bounds__(256)
void LocalAffinity_kernel(const float* __restrict__ in, float* __restrict__ out) {
    // Grid: 2(k) * 52(t) * 64(z) = 6656 blocks.
    // k = bid & 1: round-robin XCD dispatch pins each k's 4 MB input plane
    // to a fixed set of XCD L2s (4 MB each - one k-plane fits).
    const int bid  = blockIdx.x;
    const int k    = bid & 1;
    const int rest = bid >> 1;           // 0..3327 = z*52 + t
    const int t    = rest % TAPS;
    const int z    = rest / TAPS;

    // Decode tap t -> (d, di, dj, dk). All block-uniform (scalar).
    const int d   = (t < 26) ? 1 : 2;
    const int t26 = (t < 26) ? t : t - 26;
    const int ras = (t26 < 13) ? t26 : t26 + 1;   // re-insert skipped center
    const int di  = ras / 9 - 1;
    const int dj  = (ras % 9) / 3 - 1;
    const int dk  = (ras % 3) - 1;
    const int dkd = dk * d;
    const int dy  = dj * d;
    const int zc  = iclamp(z + di * d, 0, Dz - 1);

    const float* __restrict__ ctr = in + k * DHW + z  * HW;  // center z-plane
    const float* __restrict__ src = in + k * DHW + zc * HW;  // shifted z-plane
    float* __restrict__ o = out + (size_t)(k * TAPS + t) * (size_t)DHW
                                + (size_t)z * HW;

    const int tid = threadIdx.x;

    #pragma unroll
    for (int i = 0; i < 16; ++i) {
        const int pos = (i << 8) | tid;   // float4 slot in z-slice, [0,4096)
        const int y   = pos >> 5;
        const int x4  = pos & 31;
        const int x0  = x4 << 2;

        const floatx4 c = *(const floatx4*)(ctr + y * Wx + x0);

        const int yc = iclamp(y + dy, 0, Hy - 1);
        const float* row = src + yc * Wx;

        floatx4 s;
        if (dkd == 0) {
            s = *(const floatx4*)(row + x0);
        } else {
            // Dword-aligned vector load at the shifted position, start
            // clamped into the row; repair the 1-2 clamped lanes.
            const int xs  = x0 + dkd;
            const int xsa = iclamp(xs, 0, Wx - 4);
            const floatx4 v = *(const floatx4_u*)(row + xsa);
            s = v;
            if (dkd < 0) {                 // block-uniform branch
                const bool e = (x4 == 0);  // per-lane predication only here
                if (dkd == -1) {
                    if (e) { s.x = v.x; s.y = v.x; s.z = v.y; s.w = v.z; }
                } else {                   // dkd == -2
                    if (e) { s.x = v.x; s.y = v.x; s.z = v.x; s.w = v.y; }
                }
            } else {
                const bool e = (x4 == 31);
                if (dkd == 1) {
                    if (e) { s.x = v.y; s.y = v.z; s.z = v.w; s.w = v.w; }
                } else {                   // dkd == 2
                    if (e) { s.x = v.z; s.y = v.w; s.z = v.w; s.w = v.w; }
                }
            }
        }

        floatx4 r;
        r.x = c.x - s.x; r.y = c.y - s.y; r.z = c.z - s.z; r.w = c.w - s.w;
        *(floatx4*)(o + (size_t)pos * 4) = r;   // plain cached store
    }
}

extern "C" void kernel_launch(void* const* d_in, const int* in_sizes, int n_in,
                              void* d_out, int out_size, void* d_ws, size_t ws_size,
                              hipStream_t stream) {
    const float* x = (const float*)d_in[0];
    float* out = (float*)d_out;
    LocalAffinity_kernel<<<2 * TAPS * Dz, 256, 0, stream>>>(x, out);
}

// Round 4
// 432.953 us; speedup vs baseline: 1.0973x; 1.0902x over previous
//
#include <hip/hip_runtime.h>

// LocalAffinity: out[k,t,z,y,x] = x[k,z,y,x] - x[k,clamp(z+di*d),clamp(y+dj*d),clamp(x+dk*d)]
// 26 taps (raster (i,j,k) minus center) at d=1 then d=2. B=1,K=2,D=64,H=128,W=128.
// R4 = R3 resubmit (R3 was an infra failure, kernel never ran).
// Theory: vmcnt retires IN ORDER, so any load-wait drains all prior stores in
// the wave -> store depth ~1-2 in R2's load/load/store loop (2.3 TB/s vs fill's
// 6.1 TB/s which never waits). Fix: hoist ALL 18 row loads before the 52-tap
// store burst; x-shifts via wave shuffles (lgkmcnt - doesn't drain stores).

constexpr int Dz   = 64;
constexpr int Hy   = 128;
constexpr int Wx   = 128;
constexpr int HW   = Hy * Wx;        // 16384
constexpr int DHW  = Dz * HW;        // 1048576
constexpr int TAPS = 52;

typedef float floatx4 __attribute__((ext_vector_type(4)));

__device__ __forceinline__ int iclamp(int v, int lo, int hi) {
    return v < lo ? lo : (v > hi ? hi : v);
}

__global__ __launch_bounds__(256)
void LocalAffinity_kernel(const float* __restrict__ in, float* __restrict__ out) {
    // Grid 2048 = 2(k) x 64(z) x 16(y-group). k = bid&1 -> XCD parity pins
    // each k's 4 MB input plane; one thread = one (z,y,x0..x0+3) position,
    // 18 hoisted loads -> 52 stores.
    const int b   = blockIdx.x;
    const int k   = b & 1;
    const int r2  = b >> 1;            // 0..1023
    const int z   = r2 & 63;
    const int yg  = r2 >> 6;           // 0..15
    const int tid = threadIdx.x;
    const int y   = (yg << 3) | (tid >> 5);
    const int x4  = tid & 31;
    const int x0  = x4 << 2;

    const float* __restrict__ base = in + k * DHW;

    // ---- Phase 1: ALL loads (fully unrolled -> constant indices -> registers)
    floatx4 r[2][3][3];
    #pragma unroll
    for (int dd = 0; dd < 2; ++dd) {
        const int d = dd + 1;
        #pragma unroll
        for (int di = -1; di <= 1; ++di) {
            #pragma unroll
            for (int dj = -1; dj <= 1; ++dj) {
                const int zc = iclamp(z + di * d, 0, Dz - 1);
                const int yc = iclamp(y + dj * d, 0, Hy - 1);
                r[dd][di + 1][dj + 1] =
                    *(const floatx4*)(base + (zc * Hy + yc) * Wx + x0);
            }
        }
    }
    const floatx4 c = r[0][1][1];

    float* __restrict__ obase = out + (size_t)k * ((size_t)TAPS * DHW)
                                    + (size_t)((z * Hy + y) * Wx + x0);

    // ---- Phase 2: pure store burst (52 taps), shuffles only (lgkmcnt)
    #pragma unroll
    for (int dd = 0; dd < 2; ++dd) {
        #pragma unroll
        for (int di = -1; di <= 1; ++di) {
            #pragma unroll
            for (int dj = -1; dj <= 1; ++dj) {
                const floatx4 v = r[dd][di + 1][dj + 1];
                #pragma unroll
                for (int dk = -1; dk <= 1; ++dk) {
                    if (di == 0 && dj == 0 && dk == 0) continue;
                    const int raster = (di + 1) * 9 + (dj + 1) * 3 + (dk + 1);
                    const int t26    = raster < 13 ? raster : raster - 1;
                    const int t      = t26 + dd * 26;

                    floatx4 s;
                    if (dk == 0) {
                        s = v;
                    } else if (dk < 0) {
                        if (dd == 0) {                 // shift -1
                            float sm = __shfl_up(v.w, 1);
                            sm = (x4 == 0) ? v.x : sm; // x-clamp at left edge
                            s.x = sm; s.y = v.x; s.z = v.y; s.w = v.z;
                        } else {                       // shift -2
                            float a  = __shfl_up(v.z, 1);
                            float bb = __shfl_up(v.w, 1);
                            a  = (x4 == 0) ? v.x : a;
                            bb = (x4 == 0) ? v.x : bb;
                            s.x = a; s.y = bb; s.z = v.x; s.w = v.y;
                        }
                    } else {
                        if (dd == 0) {                 // shift +1
                            float sp = __shfl_down(v.x, 1);
                            sp = (x4 == 31) ? v.w : sp; // x-clamp at right edge
                            s.x = v.y; s.y = v.z; s.z = v.w; s.w = sp;
                        } else {                       // shift +2
                            float a  = __shfl_down(v.x, 1);
                            float bb = __shfl_down(v.y, 1);
                            a  = (x4 == 31) ? v.w : a;
                            bb = (x4 == 31) ? v.w : bb;
                            s.x = v.z; s.y = v.w; s.z = a; s.w = bb;
                        }
                    }

                    floatx4 o;
                    o.x = c.x - s.x; o.y = c.y - s.y;
                    o.z = c.z - s.z; o.w = c.w - s.w;
                    *(floatx4*)(obase + (size_t)t * DHW) = o;  // plain store
                }
            }
        }
    }
}

extern "C" void kernel_launch(void* const* d_in, const int* in_sizes, int n_in,
                              void* d_out, int out_size, void* d_ws, size_t ws_size,
                              hipStream_t stream) {
    const float* x = (const float*)d_in[0];
    float* out = (float*)d_out;
    LocalAffinity_kernel<<<2048, 256, 0, stream>>>(x, out);
}

// Round 5
// 427.079 us; speedup vs baseline: 1.1124x; 1.0138x over previous
//
#include <hip/hip_runtime.h>

// LocalAffinity: out[k,t,z,y,x] = x[k,z,y,x] - x[k,clamp(z+di*d),clamp(y+dj*d),clamp(x+dk*d)]
// 26 taps (raster (i,j,k) minus center) at d=1 then d=2. B=1,K=2,D=64,H=128,W=128.
// R5 theory: all prior variants cap at ~2.8 TB/s writes while the fill hits 6.2.
// Remaining difference: write-window compactness. Prior grids had ~50+ 4MB-strided
// output streams active at once -> L2 write-allocate evictions reach HBM scattered
// -> row-buffer thrash. Fix: bid sweeps the output LINEARLY; one block = one 16 KB
// contiguous output chunk; concurrent blocks form a compact ~8 MB sliding window.
// Keeps R4's win: all loads hoisted before the pure store burst.

constexpr int Dz   = 64;
constexpr int Hy   = 128;
constexpr int Wx   = 128;
constexpr int HW   = Hy * Wx;        // 16384
constexpr int DHW  = Dz * HW;        // 1048576
constexpr int TAPS = 52;

typedef float floatx4   __attribute__((ext_vector_type(4)));
typedef float floatx4_u __attribute__((ext_vector_type(4), aligned(4)));

__device__ __forceinline__ int iclamp(int v, int lo, int hi) {
    return v < lo ? lo : (v > hi ? hi : v);
}

__global__ __launch_bounds__(256)
void LocalAffinity_kernel(const float* __restrict__ in, float* __restrict__ out) {
    // bid is LINEAR in the output: bid = ((k*52 + t)*64 + z)*4 + q.
    // q = y-quarter (32 rows = 16 KB). Consecutive bids write consecutive 16 KB.
    const int bid = blockIdx.x;
    const int q   = bid & 3;
    const int z   = (bid >> 2) & 63;
    const int b3  = bid >> 8;          // 0..103 = k*52 + t
    const int t   = b3 % TAPS;
    const int k   = b3 / TAPS;

    // Decode tap t -> (d, di, dj, dk). Block-uniform (scalar).
    const int d   = (t < 26) ? 1 : 2;
    const int t26 = (t < 26) ? t : t - 26;
    const int ras = (t26 < 13) ? t26 : t26 + 1;   // re-insert skipped center
    const int di  = ras / 9 - 1;
    const int dj  = (ras % 9) / 3 - 1;
    const int dk  = (ras % 3) - 1;
    const int dkd = dk * d;
    const int dy  = dj * d;
    const int zc  = iclamp(z + di * d, 0, Dz - 1);

    const float* __restrict__ ctr = in + k * DHW + z  * HW;  // center z-plane
    const float* __restrict__ src = in + k * DHW + zc * HW;  // shifted z-plane

    const int tid = threadIdx.x;
    const int x4  = tid & 31;
    const int x0  = x4 << 2;
    const int yb  = (q << 5) | (tid >> 5);   // base y for p=0 (rows step by 8)

    // ---- Phase 1: ALL 8 loads hoisted (4 center quads + 4 shifted quads)
    floatx4 c[4], s[4];
    #pragma unroll
    for (int p = 0; p < 4; ++p) {
        const int y = yb + (p << 3);
        c[p] = *(const floatx4*)(ctr + y * Wx + x0);
    }
    #pragma unroll
    for (int p = 0; p < 4; ++p) {
        const int y  = yb + (p << 3);
        const int yc = iclamp(y + dy, 0, Hy - 1);
        const float* row = src + yc * Wx;
        if (dkd == 0) {
            s[p] = *(const floatx4*)(row + x0);
        } else {
            // Dword-aligned vector load at shifted position, start clamped
            // into the row; repair the 1-2 clamped lanes (verified in R2).
            const int xsa = iclamp(x0 + dkd, 0, Wx - 4);
            const floatx4 v = *(const floatx4_u*)(row + xsa);
            floatx4 sv = v;
            if (dkd < 0) {                 // block-uniform branch
                const bool e = (x4 == 0);  // per-lane predication only here
                if (dkd == -1) {
                    if (e) { sv.x = v.x; sv.y = v.x; sv.z = v.y; sv.w = v.z; }
                } else {                   // dkd == -2
                    if (e) { sv.x = v.x; sv.y = v.x; sv.z = v.x; sv.w = v.y; }
                }
            } else {
                const bool e = (x4 == 31);
                if (dkd == 1) {
                    if (e) { sv.x = v.y; sv.y = v.z; sv.z = v.w; sv.w = v.w; }
                } else {                   // dkd == 2
                    if (e) { sv.x = v.z; sv.y = v.w; sv.z = v.w; sv.w = v.w; }
                }
            }
            s[p] = sv;
        }
    }

    // ---- Phase 2: pure store burst, 16 KB contiguous per block
    float* __restrict__ obase = out + (size_t)(k * TAPS + t) * (size_t)DHW
                                    + (size_t)z * HW;
    #pragma unroll
    for (int p = 0; p < 4; ++p) {
        const int y = yb + (p << 3);
        floatx4 r;
        r.x = c[p].x - s[p].x; r.y = c[p].y - s[p].y;
        r.z = c[p].z - s[p].z; r.w = c[p].w - s[p].w;
        *(floatx4*)(obase + y * Wx + x0) = r;
    }
}

extern "C" void kernel_launch(void* const* d_in, const int* in_sizes, int n_in,
                              void* d_out, int out_size, void* d_ws, size_t ws_size,
                              hipStream_t stream) {
    const float* x = (const float*)d_in[0];
    float* out = (float*)d_out;
    LocalAffinity_kernel<<<2 * TAPS * Dz * 4, 256, 0, stream>>>(x, out);
}

// Round 6
// 422.292 us; speedup vs baseline: 1.1250x; 1.0113x over previous
//
#include <hip/hip_runtime.h>

// LocalAffinity: out[k,t,z,y,x] = x[k,z,y,x] - x[k,clamp(z+di*d),clamp(y+dj*d),clamp(x+dk*d)]
// 26 taps (raster (i,j,k) minus center) at d=1 then d=2. B=1,K=2,D=64,H=128,W=128.
// R6 = R5 structure, ONE change: nontemporal stores.
// Theory: plain stores write-allocate in L2 -> RFO fetches each output line
// from HBM first. 436MB write + 436MB RFO + 8MB input = 880MB @ 6.3TB/s
// = 140us ~= measured 148us. nt bypasses write-allocate -> ~75-85us kernel.
// (R1/R2's nt-vs-plain A/B was confounded by the store-drain defect.)

constexpr int Dz   = 64;
constexpr int Hy   = 128;
constexpr int Wx   = 128;
constexpr int HW   = Hy * Wx;        // 16384
constexpr int DHW  = Dz * HW;        // 1048576
constexpr int TAPS = 52;

typedef float floatx4   __attribute__((ext_vector_type(4)));
typedef float floatx4_u __attribute__((ext_vector_type(4), aligned(4)));

__device__ __forceinline__ int iclamp(int v, int lo, int hi) {
    return v < lo ? lo : (v > hi ? hi : v);
}

__global__ __launch_bounds__(256)
void LocalAffinity_kernel(const float* __restrict__ in, float* __restrict__ out) {
    // bid is LINEAR in the output: bid = ((k*52 + t)*64 + z)*4 + q.
    // q = y-quarter (32 rows = 16 KB). Consecutive bids write consecutive 16 KB.
    const int bid = blockIdx.x;
    const int q   = bid & 3;
    const int z   = (bid >> 2) & 63;
    const int b3  = bid >> 8;          // 0..103 = k*52 + t
    const int t   = b3 % TAPS;
    const int k   = b3 / TAPS;

    // Decode tap t -> (d, di, dj, dk). Block-uniform (scalar).
    const int d   = (t < 26) ? 1 : 2;
    const int t26 = (t < 26) ? t : t - 26;
    const int ras = (t26 < 13) ? t26 : t26 + 1;   // re-insert skipped center
    const int di  = ras / 9 - 1;
    const int dj  = (ras % 9) / 3 - 1;
    const int dk  = (ras % 3) - 1;
    const int dkd = dk * d;
    const int dy  = dj * d;
    const int zc  = iclamp(z + di * d, 0, Dz - 1);

    const float* __restrict__ ctr = in + k * DHW + z  * HW;  // center z-plane
    const float* __restrict__ src = in + k * DHW + zc * HW;  // shifted z-plane

    const int tid = threadIdx.x;
    const int x4  = tid & 31;
    const int x0  = x4 << 2;
    const int yb  = (q << 5) | (tid >> 5);   // base y for p=0 (rows step by 8)

    // ---- Phase 1: ALL 8 loads hoisted (4 center quads + 4 shifted quads)
    floatx4 c[4], s[4];
    #pragma unroll
    for (int p = 0; p < 4; ++p) {
        const int y = yb + (p << 3);
        c[p] = *(const floatx4*)(ctr + y * Wx + x0);
    }
    #pragma unroll
    for (int p = 0; p < 4; ++p) {
        const int y  = yb + (p << 3);
        const int yc = iclamp(y + dy, 0, Hy - 1);
        const float* row = src + yc * Wx;
        if (dkd == 0) {
            s[p] = *(const floatx4*)(row + x0);
        } else {
            // Dword-aligned vector load at shifted position, start clamped
            // into the row; repair the 1-2 clamped lanes (verified in R2).
            const int xsa = iclamp(x0 + dkd, 0, Wx - 4);
            const floatx4 v = *(const floatx4_u*)(row + xsa);
            floatx4 sv = v;
            if (dkd < 0) {                 // block-uniform branch
                const bool e = (x4 == 0);  // per-lane predication only here
                if (dkd == -1) {
                    if (e) { sv.x = v.x; sv.y = v.x; sv.z = v.y; sv.w = v.z; }
                } else {                   // dkd == -2
                    if (e) { sv.x = v.x; sv.y = v.x; sv.z = v.x; sv.w = v.y; }
                }
            } else {
                const bool e = (x4 == 31);
                if (dkd == 1) {
                    if (e) { sv.x = v.y; sv.y = v.z; sv.z = v.w; sv.w = v.w; }
                } else {                   // dkd == 2
                    if (e) { sv.x = v.z; sv.y = v.w; sv.z = v.w; sv.w = v.w; }
                }
            }
            s[p] = sv;
        }
    }

    // ---- Phase 2: pure nt-store burst, 16 KB contiguous per block
    float* __restrict__ obase = out + (size_t)(k * TAPS + t) * (size_t)DHW
                                    + (size_t)z * HW;
    #pragma unroll
    for (int p = 0; p < 4; ++p) {
        const int y = yb + (p << 3);
        floatx4 r;
        r.x = c[p].x - s[p].x; r.y = c[p].y - s[p].y;
        r.z = c[p].z - s[p].z; r.w = c[p].w - s[p].w;
        __builtin_nontemporal_store(r, (floatx4*)(obase + y * Wx + x0));
    }
}

extern "C" void kernel_launch(void* const* d_in, const int* in_sizes, int n_in,
                              void* d_out, int out_size, void* d_ws, size_t ws_size,
                              hipStream_t stream) {
    const float* x = (const float*)d_in[0];
    float* out = (float*)d_out;
    LocalAffinity_kernel<<<2 * TAPS * Dz * 4, 256, 0, stream>>>(x, out);
}